// Round 6
// baseline (1091.212 us; speedup 1.0000x reference)
//
#include <hip/hip_runtime.h>

#define NN 50000
#define NH 4
#define NR 6
#define NE 300000
#define HD 256     // NH*DHD
#define SLOTS 32   // max degree per (relation,node); P(deg>32) ~ 1e-14
#define CHUNKS 64
#define CHSZ ((NE + CHUNKS - 1) / CHUNKS)  // 4688

typedef __attribute__((ext_vector_type(4))) float f32x4;
typedef __attribute__((ext_vector_type(8))) short bf16x8;

__device__ __forceinline__ short f2bf(float f) {
  unsigned u = __float_as_uint(f);
  unsigned r = (u + 0x7FFFu + ((u >> 16) & 1u)) >> 16;  // round-nearest-even
  return (short)r;
}
__device__ __forceinline__ float bf2f(unsigned short s) {
  return __uint_as_float(((unsigned)s) << 16);
}

// ---------------- cast x -> bf16 ------------------------------------------
__global__ __launch_bounds__(256) void cast_x_kernel(
    const float* __restrict__ x, short* __restrict__ xb, int n4) {
  const int i = blockIdx.x * 256 + threadIdx.x;
  if (i >= n4) return;
  const float4 v = ((const float4*)x)[i];
  short4 o;
  o.x = f2bf(v.x); o.y = f2bf(v.y); o.z = f2bf(v.z); o.w = f2bf(v.w);
  ((short4*)xb)[i] = o;
}

// ---------------- cast + transpose W -> Wt[r][n][k] bf16 ------------------
__global__ __launch_bounds__(256) void cast_wt_kernel(
    const float* __restrict__ W, short* __restrict__ wt) {
  const int o = blockIdx.x * 256 + threadIdx.x;  // over NR*256*256
  if (o >= NR * 256 * 256) return;
  const int r = o >> 16;
  const int nrow = (o >> 8) & 255;
  const int k = o & 255;
  wt[o] = f2bf(W[r * 65536 + k * 256 + nrow]);
}

// ---------------- vl/vr: fold attn into W --------------------------------
// vl[r][h][k] = sum_d W[r][k][h*64+d] * attn_l[r][h][d]  (fp32)
__global__ __launch_bounds__(256) void prep_v_kernel(
    const float* __restrict__ W, const float* __restrict__ attn_l,
    const float* __restrict__ attn_r, float* __restrict__ vl,
    float* __restrict__ vr) {
  const int id = blockIdx.x * 256 + threadIdx.x;  // NR*NH*256 = 6144
  if (id >= NR * NH * 256) return;
  const int k = id & 255, h = (id >> 8) & 3, r = id >> 10;
  const float* wrow = W + ((size_t)r * 256 + k) * 256 + h * 64;
  const float* al = attn_l + (r * 4 + h) * 64;
  const float* ar = attn_r + (r * 4 + h) * 64;
  float sl = 0.f, sr = 0.f;
#pragma unroll 8
  for (int d = 0; d < 64; ++d) {
    const float wv = wrow[d];
    sl = fmaf(wv, al[d], sl);
    sr = fmaf(wv, ar[d], sr);
  }
  vl[id] = sl;  // layout [r][h][k]
  vr[id] = sr;
}

// ---------------- el/er: per-node logits via x . v ------------------------
// Block = 16 nodes; wave w handles nodes w*4..w*4+3. el/er stored as float4
// per (r,node): el[((r*NN)+n)*4 + h].
__global__ __launch_bounds__(256) void eler_kernel(
    const short* __restrict__ xb, const float* __restrict__ vl,
    const float* __restrict__ vr, float* __restrict__ el,
    float* __restrict__ er) {
  const int t = threadIdx.x, lane = t & 63, w = t >> 6;
  const int nb = blockIdx.x * 16;
  for (int ni = 0; ni < 4; ++ni) {
    const int n = nb + w * 4 + ni;
    const ushort4 xr = ((const ushort4*)xb)[(size_t)n * 64 + lane];
    const float fx0 = bf2f(xr.x), fx1 = bf2f(xr.y);
    const float fx2 = bf2f(xr.z), fx3 = bf2f(xr.w);
    for (int r = 0; r < NR; ++r) {
      float pl[4], pr[4];
#pragma unroll
      for (int h = 0; h < 4; ++h) {
        const float4 v4 = ((const float4*)vl)[(r * 4 + h) * 64 + lane];
        const float4 u4 = ((const float4*)vr)[(r * 4 + h) * 64 + lane];
        pl[h] = fx0 * v4.x + fx1 * v4.y + fx2 * v4.z + fx3 * v4.w;
        pr[h] = fx0 * u4.x + fx1 * u4.y + fx2 * u4.z + fx3 * u4.w;
      }
#pragma unroll
      for (int m = 1; m < 64; m <<= 1) {
#pragma unroll
        for (int h = 0; h < 4; ++h) {
          pl[h] += __shfl_xor(pl[h], m, 64);
          pr[h] += __shfl_xor(pr[h], m, 64);
        }
      }
      if (lane == 0) {
        float4 a = {pl[0], pl[1], pl[2], pl[3]};
        float4 b = {pr[0], pr[1], pr[2], pr[3]};
        ((float4*)el)[r * NN + n] = a;
        ((float4*)er)[r * NN + n] = b;
      }
    }
  }
}

// ---------------- pack edges to u32 (dst<<16 | src) -----------------------
// NOTE: harness delivers integer inputs as int32 (NOT the reference's int64).
__global__ __launch_bounds__(256) void pack_kernel(
    const int* __restrict__ src, const int* __restrict__ dst,
    unsigned* __restrict__ pe) {
  const int i = blockIdx.x * 256 + threadIdx.x;
  if (i < NR * NE)
    pe[i] = ((unsigned)dst[i] << 16) | (unsigned)src[i];
}

// ---------------- single-pass fixed-slot bucket build ---------------------
// 8 dst-range groups (linear blockIdx%8 ~ XCD round-robin): atomics + slot
// lines for one contiguous deg/slots segment stay in one XCD's L2.
// pe is 7.2 MB -> the 8x re-read is L3-served.
__global__ __launch_bounds__(256) void build_kernel(
    const unsigned* __restrict__ pe, int* __restrict__ deg,
    unsigned short* __restrict__ slots) {
  const int grp = blockIdx.x & 7;
  const int chunk = blockIdx.x >> 3;
  const int lo = chunk * CHSZ;
  const int hi = (lo + CHSZ < NE) ? lo + CHSZ : NE;
  const unsigned dlo = grp * (NN / 8);
  for (int r = 0; r < NR; ++r) {
    for (int i = lo + threadIdx.x; i < hi; i += 256) {
      const unsigned p = pe[(size_t)r * NE + i];
      const unsigned d = p >> 16;
      if (d - dlo < (unsigned)(NN / 8)) {
        const int g = r * NN + (int)d;
        const int sl = atomicAdd(&deg[g], 1);
        if (sl < SLOTS)
          slots[(size_t)g * SLOTS + sl] = (unsigned short)(p & 0xffffu);
      }
    }
  }
}

// ---------------- fused gather-aggregate + projection ---------------------
// Block = 16 dst nodes (grid 3125, exact). Per relation:
//  q-phase: wave w handles 4 nodes; per edge gather xb[src] row (512B/wave,
//           25.6MB L3-resident set) weighted by 4 head-alphas -> q_rh.
//           Normalized q -> LDS as bf16 in MFMA-A layout.
//  mfma-phase: wave w == head w: [16,256] @ Wt_r[head w cols][256] via
//           16x16x32 MFMA, B-frags straight from L2-hot global Wt.
//  oacc += relu(c + bias); single out write after all relations.
__global__ __launch_bounds__(256) void agg_kernel(
    const short* __restrict__ xb, const short* __restrict__ wt,
    const float* __restrict__ el, const float* __restrict__ er,
    const int* __restrict__ deg, const unsigned short* __restrict__ slots,
    const float* __restrict__ bias, float* __restrict__ out) {
  __shared__ short qs[4 * 16 * 264];  // [head][node16][256 +8 pad] = 33 KB
  const int t = threadIdx.x, lane = t & 63, w = t >> 6;
  const int nb = blockIdx.x * 16;
  const int ra = lane & 15, qa = (lane >> 4) * 8;

  f32x4 oacc[4];
#pragma unroll
  for (int i = 0; i < 4; ++i) {
    f32x4 z = {0.f, 0.f, 0.f, 0.f};
    oacc[i] = z;
  }

  for (int r = 0; r < NR; ++r) {
    __syncthreads();  // qs safe to overwrite (prev relation's reads done)
    // ---- q phase ----
    for (int ni = 0; ni < 4; ++ni) {
      const int nl = w * 4 + ni;
      const int n = nb + nl;
      const int g = r * NN + n;
      const float4 er4 = ((const float4*)er)[g];
      int dg = deg[g];
      dg = dg > SLOTS ? SLOTS : dg;
      const unsigned short* slp = slots + (size_t)g * SLOTS;
      float qv[4][4];
#pragma unroll
      for (int h = 0; h < 4; ++h)
#pragma unroll
        for (int c = 0; c < 4; ++c) qv[h][c] = 0.f;
      float zz[4] = {0.f, 0.f, 0.f, 0.f};
      for (int j = 0; j < dg; ++j) {
        const int s = slp[j];
        const float4 el4 = ((const float4*)el)[r * NN + s];
        float e0 = el4.x + er4.x, e1 = el4.y + er4.y;
        float e2 = el4.z + er4.z, e3 = el4.w + er4.w;
        e0 = e0 > 0.f ? e0 : 0.2f * e0;
        e1 = e1 > 0.f ? e1 : 0.2f * e1;
        e2 = e2 > 0.f ? e2 : 0.2f * e2;
        e3 = e3 > 0.f ? e3 : 0.2f * e3;
        const float p[4] = {__expf(e0), __expf(e1), __expf(e2), __expf(e3)};
        const ushort4 xr = ((const ushort4*)xb)[(size_t)s * 64 + lane];
        const float fx[4] = {bf2f(xr.x), bf2f(xr.y), bf2f(xr.z), bf2f(xr.w)};
        zz[0] += p[0]; zz[1] += p[1]; zz[2] += p[2]; zz[3] += p[3];
#pragma unroll
        for (int h = 0; h < 4; ++h)
#pragma unroll
          for (int c = 0; c < 4; ++c)
            qv[h][c] = fmaf(p[h], fx[c], qv[h][c]);
      }
#pragma unroll
      for (int h = 0; h < 4; ++h) {
        const float inv = 1.f / fmaxf(zz[h], 1e-9f);
        short4 sq;
        sq.x = f2bf(qv[h][0] * inv);
        sq.y = f2bf(qv[h][1] * inv);
        sq.z = f2bf(qv[h][2] * inv);
        sq.w = f2bf(qv[h][3] * inv);
        *(short4*)&qs[(h * 16 + nl) * 264 + lane * 4] = sq;
      }
    }
    __syncthreads();
    // ---- mfma phase: wave w = head w ----
    f32x4 c[4];
#pragma unroll
    for (int i = 0; i < 4; ++i) {
      f32x4 z = {0.f, 0.f, 0.f, 0.f};
      c[i] = z;
    }
    for (int ks = 0; ks < 8; ++ks) {
      const bf16x8 af = *(const bf16x8*)&qs[(w * 16 + ra) * 264 + ks * 32 + qa];
#pragma unroll
      for (int tl = 0; tl < 4; ++tl) {
        const bf16x8 bfv = *(const bf16x8*)&wt[
            ((size_t)r * 256 + w * 64 + tl * 16 + ra) * 256 + ks * 32 + qa];
        c[tl] = __builtin_amdgcn_mfma_f32_16x16x32_bf16(af, bfv, c[tl], 0, 0, 0);
      }
    }
#pragma unroll
    for (int tl = 0; tl < 4; ++tl) {
      const float b = bias[r * 256 + w * 64 + tl * 16 + ra];
#pragma unroll
      for (int j = 0; j < 4; ++j)
        oacc[tl][j] += fmaxf(c[tl][j] + b, 0.f);
    }
  }
  // ---- store ----
#pragma unroll
  for (int tl = 0; tl < 4; ++tl)
#pragma unroll
    for (int j = 0; j < 4; ++j) {
      const int row = nb + (lane >> 4) * 4 + j;
      out[(size_t)row * 256 + w * 64 + tl * 16 + ra] = oacc[tl][j];
    }
}

// ---------------------------------------------------------------------------
extern "C" void kernel_launch(void* const* d_in, const int* in_sizes, int n_in,
                              void* d_out, int out_size, void* d_ws,
                              size_t ws_size, hipStream_t stream) {
  const float* x      = (const float*)d_in[0];
  const float* W      = (const float*)d_in[1];
  const float* attn_l = (const float*)d_in[2];
  const float* attn_r = (const float*)d_in[3];
  const float* bias   = (const float*)d_in[4];
  const int*   src    = (const int*)d_in[5];   // int32 per harness contract
  const int*   dst    = (const int*)d_in[6];
  float* out = (float*)d_out;

  char* p = (char*)d_ws;
  auto alloc = [&](size_t bytes) {
    char* r = p;
    p += (bytes + 255) & ~(size_t)255;
    return r;
  };
  short* xb    = (short*)alloc((size_t)NN * HD * 2);            // 25.6 MB
  short* wt    = (short*)alloc((size_t)NR * 256 * 256 * 2);     // 0.79 MB
  float* vl    = (float*)alloc((size_t)NR * NH * 256 * 4);      // 24.6 KB
  float* vr    = (float*)alloc((size_t)NR * NH * 256 * 4);
  float* el    = (float*)alloc((size_t)NR * NN * 4 * 4);        // 4.8 MB
  float* er    = (float*)alloc((size_t)NR * NN * 4 * 4);        // 4.8 MB
  int*   deg   = (int*)alloc((size_t)NR * NN * 4);              // 1.2 MB
  unsigned short* slots =
      (unsigned short*)alloc((size_t)NR * NN * SLOTS * 2);      // 19.2 MB
  unsigned* pe = (unsigned*)alloc((size_t)NR * NE * 4);         // 7.2 MB

  hipMemsetAsync(deg, 0, (size_t)NR * NN * 4, stream);

  cast_x_kernel<<<(NN * HD / 4 + 255) / 256, 256, 0, stream>>>(x, xb,
                                                               NN * HD / 4);
  cast_wt_kernel<<<(NR * 256 * 256 + 255) / 256, 256, 0, stream>>>(W, wt);
  prep_v_kernel<<<(NR * NH * 256 + 255) / 256, 256, 0, stream>>>(W, attn_l,
                                                                 attn_r, vl,
                                                                 vr);
  pack_kernel<<<(NR * NE + 255) / 256, 256, 0, stream>>>(src, dst, pe);
  build_kernel<<<CHUNKS * 8, 256, 0, stream>>>(pe, deg, slots);
  eler_kernel<<<NN / 16, 256, 0, stream>>>(xb, vl, vr, el, er);
  agg_kernel<<<NN / 16, 256, 0, stream>>>(xb, wt, el, er, deg, slots, bias,
                                          out);
}

// Round 7
// 908.867 us; speedup vs baseline: 1.2006x; 1.2006x over previous
//
#include <hip/hip_runtime.h>

#define NN 50000
#define NH 4
#define NR 6
#define NE 300000
#define HD 256     // NH*DHD
#define SLOTS 32   // max degree per (relation,node); P(deg>32) ~ 1e-14
#define CHUNKS 64
#define CHSZ ((NE + CHUNKS - 1) / CHUNKS)  // 4688

typedef __attribute__((ext_vector_type(4))) float f32x4;
typedef __attribute__((ext_vector_type(8))) short bf16x8;

__device__ __forceinline__ short f2bf(float f) {
  unsigned u = __float_as_uint(f);
  unsigned r = (u + 0x7FFFu + ((u >> 16) & 1u)) >> 16;  // round-nearest-even
  return (short)r;
}
__device__ __forceinline__ float bf2f(unsigned short s) {
  return __uint_as_float(((unsigned)s) << 16);
}

// ---------------- cast x -> bf16 ------------------------------------------
__global__ __launch_bounds__(256) void cast_x_kernel(
    const float* __restrict__ x, short* __restrict__ xb, int n4) {
  const int i = blockIdx.x * 256 + threadIdx.x;
  if (i >= n4) return;
  const float4 v = ((const float4*)x)[i];
  short4 o;
  o.x = f2bf(v.x); o.y = f2bf(v.y); o.z = f2bf(v.z); o.w = f2bf(v.w);
  ((short4*)xb)[i] = o;
}

// ---------------- cast + transpose W -> Wt[r][n][k] bf16 ------------------
__global__ __launch_bounds__(256) void cast_wt_kernel(
    const float* __restrict__ W, short* __restrict__ wt) {
  const int o = blockIdx.x * 256 + threadIdx.x;  // over NR*256*256
  if (o >= NR * 256 * 256) return;
  const int r = o >> 16;
  const int nrow = (o >> 8) & 255;
  const int k = o & 255;
  wt[o] = f2bf(W[r * 65536 + k * 256 + nrow]);
}

// ---------------- vl/vr: fold attn into W --------------------------------
// vl[r][h][k] = sum_d W[r][k][h*64+d] * attn_l[r][h][d]  (fp32)
__global__ __launch_bounds__(256) void prep_v_kernel(
    const float* __restrict__ W, const float* __restrict__ attn_l,
    const float* __restrict__ attn_r, float* __restrict__ vl,
    float* __restrict__ vr) {
  const int id = blockIdx.x * 256 + threadIdx.x;  // NR*NH*256 = 6144
  if (id >= NR * NH * 256) return;
  const int k = id & 255, h = (id >> 8) & 3, r = id >> 10;
  const float* wrow = W + ((size_t)r * 256 + k) * 256 + h * 64;
  const float* al = attn_l + (r * 4 + h) * 64;
  const float* ar = attn_r + (r * 4 + h) * 64;
  float sl = 0.f, sr = 0.f;
#pragma unroll 8
  for (int d = 0; d < 64; ++d) {
    const float wv = wrow[d];
    sl = fmaf(wv, al[d], sl);
    sr = fmaf(wv, ar[d], sr);
  }
  vl[id] = sl;  // layout [r][h][k]
  vr[id] = sr;
}

// ---------------- el/er: per-node logits via x . v ------------------------
// Block = 16 nodes; wave w handles nodes w*4..w*4+3. el/er stored as float4
// per (r,node): el[((r*NN)+n)*4 + h].
__global__ __launch_bounds__(256) void eler_kernel(
    const short* __restrict__ xb, const float* __restrict__ vl,
    const float* __restrict__ vr, float* __restrict__ el,
    float* __restrict__ er) {
  const int t = threadIdx.x, lane = t & 63, w = t >> 6;
  const int nb = blockIdx.x * 16;
  for (int ni = 0; ni < 4; ++ni) {
    const int n = nb + w * 4 + ni;
    const ushort4 xr = ((const ushort4*)xb)[(size_t)n * 64 + lane];
    const float fx0 = bf2f(xr.x), fx1 = bf2f(xr.y);
    const float fx2 = bf2f(xr.z), fx3 = bf2f(xr.w);
    for (int r = 0; r < NR; ++r) {
      float pl[4], pr[4];
#pragma unroll
      for (int h = 0; h < 4; ++h) {
        const float4 v4 = ((const float4*)vl)[(r * 4 + h) * 64 + lane];
        const float4 u4 = ((const float4*)vr)[(r * 4 + h) * 64 + lane];
        pl[h] = fx0 * v4.x + fx1 * v4.y + fx2 * v4.z + fx3 * v4.w;
        pr[h] = fx0 * u4.x + fx1 * u4.y + fx2 * u4.z + fx3 * u4.w;
      }
#pragma unroll
      for (int m = 1; m < 64; m <<= 1) {
#pragma unroll
        for (int h = 0; h < 4; ++h) {
          pl[h] += __shfl_xor(pl[h], m, 64);
          pr[h] += __shfl_xor(pr[h], m, 64);
        }
      }
      if (lane == 0) {
        float4 a = {pl[0], pl[1], pl[2], pl[3]};
        float4 b = {pr[0], pr[1], pr[2], pr[3]};
        ((float4*)el)[r * NN + n] = a;
        ((float4*)er)[r * NN + n] = b;
      }
    }
  }
}

// ---------------- pack edges to u32 (dst<<16 | src) -----------------------
// NOTE: harness delivers integer inputs as int32 (NOT the reference's int64).
__global__ __launch_bounds__(256) void pack_kernel(
    const int* __restrict__ src, const int* __restrict__ dst,
    unsigned* __restrict__ pe) {
  const int i = blockIdx.x * 256 + threadIdx.x;
  if (i < NR * NE)
    pe[i] = ((unsigned)dst[i] << 16) | (unsigned)src[i];
}

// ---------------- single-pass fixed-slot bucket build ---------------------
__global__ __launch_bounds__(256) void build_kernel(
    const unsigned* __restrict__ pe, int* __restrict__ deg,
    unsigned short* __restrict__ slots) {
  const int grp = blockIdx.x & 7;
  const int chunk = blockIdx.x >> 3;
  const int lo = chunk * CHSZ;
  const int hi = (lo + CHSZ < NE) ? lo + CHSZ : NE;
  const unsigned dlo = grp * (NN / 8);
  for (int r = 0; r < NR; ++r) {
    for (int i = lo + threadIdx.x; i < hi; i += 256) {
      const unsigned p = pe[(size_t)r * NE + i];
      const unsigned d = p >> 16;
      if (d - dlo < (unsigned)(NN / 8)) {
        const int g = r * NN + (int)d;
        const int sl = atomicAdd(&deg[g], 1);
        if (sl < SLOTS)
          slots[(size_t)g * SLOTS + sl] = (unsigned short)(p & 0xffffu);
      }
    }
  }
}

// ---------------- fused gather-aggregate + projection ---------------------
// Block = 1024 threads = 16 waves = 16 dst nodes (grid 3125 exact).
// Per relation:
//  q-phase: wave w owns node nb+w; slot row pre-loaded into lane regs,
//           per edge: s via __shfl, el4 broadcast load, xb row gather
//           (512 B/wave); alpha-weighted accumulate into qv[4 heads][4].
//           Normalized q -> qs LDS (bf16, MFMA-A layout).
//  mfma-phase: wave w -> (head h=w&3, coltile tl=w>>2): one 16x16 C-tile,
//           A from qs, B straight from L2-hot global Wt. 8 MFMAs.
//  oacc (one f32x4) += relu(c + bias); single out write after all relations.
// VGPR ~50 -> __launch_bounds__(1024,8) = 2 blocks/CU = 32 waves (100% occ).
__global__ __launch_bounds__(1024, 8) void agg_kernel(
    const short* __restrict__ xb, const short* __restrict__ wt,
    const float* __restrict__ el, const float* __restrict__ er,
    const int* __restrict__ deg, const unsigned short* __restrict__ slots,
    const float* __restrict__ bias, float* __restrict__ out) {
  __shared__ short qs[4 * 16 * 264];  // [head][node16][256 +8 pad] = 33 KB
  const int t = threadIdx.x, lane = t & 63, w = t >> 6;  // w = 0..15
  const int nb = blockIdx.x * 16;
  const int ra = lane & 15, qa = (lane >> 4) * 8;
  const int h = w & 3, tl = w >> 2;
  const int colb = h * 64 + tl * 16 + ra;  // this wave's out-column
  const int n = nb + w;                    // this wave's node (q-phase)

  f32x4 oacc = {0.f, 0.f, 0.f, 0.f};

  for (int r = 0; r < NR; ++r) {
    // ---- q phase: one wave = one node ----
    const int g = r * NN + n;
    const float4 er4 = ((const float4*)er)[g];
    int dg = deg[g];
    dg = dg > SLOTS ? SLOTS : dg;
    const unsigned short* slp = slots + (size_t)g * SLOTS;
    const int sv = (lane < SLOTS) ? (int)slp[lane] : 0;  // slot row in regs
    float qv[4][4];
#pragma unroll
    for (int hh = 0; hh < 4; ++hh)
#pragma unroll
      for (int c = 0; c < 4; ++c) qv[hh][c] = 0.f;
    float zz[4] = {0.f, 0.f, 0.f, 0.f};
    for (int j = 0; j < dg; ++j) {
      const int s = __shfl(sv, j, 64);
      const float4 el4 = ((const float4*)el)[r * NN + s];
      float e0 = el4.x + er4.x, e1 = el4.y + er4.y;
      float e2 = el4.z + er4.z, e3 = el4.w + er4.w;
      e0 = e0 > 0.f ? e0 : 0.2f * e0;  // leaky_relu(0.2)
      e1 = e1 > 0.f ? e1 : 0.2f * e1;
      e2 = e2 > 0.f ? e2 : 0.2f * e2;
      e3 = e3 > 0.f ? e3 : 0.2f * e3;
      const float p[4] = {__expf(e0), __expf(e1), __expf(e2), __expf(e3)};
      const ushort4 xr = ((const ushort4*)xb)[(size_t)s * 64 + lane];
      const float fx[4] = {bf2f(xr.x), bf2f(xr.y), bf2f(xr.z), bf2f(xr.w)};
      zz[0] += p[0]; zz[1] += p[1]; zz[2] += p[2]; zz[3] += p[3];
#pragma unroll
      for (int hh = 0; hh < 4; ++hh)
#pragma unroll
        for (int c = 0; c < 4; ++c)
          qv[hh][c] = fmaf(p[hh], fx[c], qv[hh][c]);
    }
#pragma unroll
    for (int hh = 0; hh < 4; ++hh) {
      const float inv = 1.f / fmaxf(zz[hh], 1e-9f);
      short4 sq;
      sq.x = f2bf(qv[hh][0] * inv);
      sq.y = f2bf(qv[hh][1] * inv);
      sq.z = f2bf(qv[hh][2] * inv);
      sq.w = f2bf(qv[hh][3] * inv);
      *(short4*)&qs[(hh * 16 + w) * 264 + lane * 4] = sq;
    }
    __syncthreads();
    // ---- mfma phase: wave w -> C-tile (head h, coltile tl) ----
    f32x4 c = {0.f, 0.f, 0.f, 0.f};
    const short* wtb = wt + ((size_t)r * 256 + colb) * 256;
#pragma unroll
    for (int ks = 0; ks < 8; ++ks) {
      const bf16x8 af = *(const bf16x8*)&qs[(h * 16 + ra) * 264 + ks * 32 + qa];
      const bf16x8 bfv = *(const bf16x8*)&wtb[ks * 32 + qa];
      c = __builtin_amdgcn_mfma_f32_16x16x32_bf16(af, bfv, c, 0, 0, 0);
    }
    const float b = bias[r * 256 + colb];
#pragma unroll
    for (int j = 0; j < 4; ++j) oacc[j] += fmaxf(c[j] + b, 0.f);
    __syncthreads();  // qs safe to overwrite next relation
  }
  // ---- store: row = nb + quad*4 + j, col = colb ----
#pragma unroll
  for (int j = 0; j < 4; ++j) {
    const int row = nb + (lane >> 4) * 4 + j;
    out[(size_t)row * 256 + colb] = oacc[j];
  }
}

// ---------------------------------------------------------------------------
extern "C" void kernel_launch(void* const* d_in, const int* in_sizes, int n_in,
                              void* d_out, int out_size, void* d_ws,
                              size_t ws_size, hipStream_t stream) {
  const float* x      = (const float*)d_in[0];
  const float* W      = (const float*)d_in[1];
  const float* attn_l = (const float*)d_in[2];
  const float* attn_r = (const float*)d_in[3];
  const float* bias   = (const float*)d_in[4];
  const int*   src    = (const int*)d_in[5];   // int32 per harness contract
  const int*   dst    = (const int*)d_in[6];
  float* out = (float*)d_out;

  char* p = (char*)d_ws;
  auto alloc = [&](size_t bytes) {
    char* r = p;
    p += (bytes + 255) & ~(size_t)255;
    return r;
  };
  short* xb    = (short*)alloc((size_t)NN * HD * 2);            // 25.6 MB
  short* wt    = (short*)alloc((size_t)NR * 256 * 256 * 2);     // 0.79 MB
  float* vl    = (float*)alloc((size_t)NR * NH * 256 * 4);      // 24.6 KB
  float* vr    = (float*)alloc((size_t)NR * NH * 256 * 4);
  float* el    = (float*)alloc((size_t)NR * NN * 4 * 4);        // 4.8 MB
  float* er    = (float*)alloc((size_t)NR * NN * 4 * 4);        // 4.8 MB
  int*   deg   = (int*)alloc((size_t)NR * NN * 4);              // 1.2 MB
  unsigned short* slots =
      (unsigned short*)alloc((size_t)NR * NN * SLOTS * 2);      // 19.2 MB
  unsigned* pe = (unsigned*)alloc((size_t)NR * NE * 4);         // 7.2 MB

  hipMemsetAsync(deg, 0, (size_t)NR * NN * 4, stream);

  cast_x_kernel<<<(NN * HD / 4 + 255) / 256, 256, 0, stream>>>(x, xb,
                                                               NN * HD / 4);
  cast_wt_kernel<<<(NR * 256 * 256 + 255) / 256, 256, 0, stream>>>(W, wt);
  prep_v_kernel<<<(NR * NH * 256 + 255) / 256, 256, 0, stream>>>(W, attn_l,
                                                                 attn_r, vl,
                                                                 vr);
  pack_kernel<<<(NR * NE + 255) / 256, 256, 0, stream>>>(src, dst, pe);
  build_kernel<<<CHUNKS * 8, 256, 0, stream>>>(pe, deg, slots);
  eler_kernel<<<NN / 16, 256, 0, stream>>>(xb, vl, vr, el, er);
  agg_kernel<<<NN / 16, 1024, 0, stream>>>(xb, wt, el, er, deg, slots, bias,
                                           out);
}

// Round 8
// 475.437 us; speedup vs baseline: 2.2952x; 1.9116x over previous
//
#include <hip/hip_runtime.h>

#define NN 50000
#define MP 50048   // padded to 391*128
#define NH 4
#define NR 6
#define NE 300000
#define HD 256     // NH*DHD
#define SLOTS 32   // max degree per (relation,node); P(deg>32) ~ 1e-14
#define CHUNKS 64
#define CHSZ ((NE + CHUNKS - 1) / CHUNKS)  // 4688

typedef __attribute__((ext_vector_type(4))) float f32x4;
typedef __attribute__((ext_vector_type(8))) short bf16x8;

__device__ __forceinline__ short f2bf(float f) {
  unsigned u = __float_as_uint(f);
  unsigned r = (u + 0x7FFFu + ((u >> 16) & 1u)) >> 16;  // round-nearest-even
  return (short)r;
}
__device__ __forceinline__ float bf2f_lo(unsigned d) {
  return __uint_as_float(d << 16);
}
__device__ __forceinline__ float bf2f_hi(unsigned d) {
  return __uint_as_float(d & 0xffff0000u);
}

#define GLOAD_LDS16(g, l)                                                     \
  __builtin_amdgcn_global_load_lds(                                           \
      (const __attribute__((address_space(1))) void*)(g),                     \
      (__attribute__((address_space(3))) void*)(l), 16, 0, 0)

// ---------------- cast x -> bf16 ------------------------------------------
__global__ __launch_bounds__(256) void cast_x_kernel(
    const float* __restrict__ x, short* __restrict__ xb, int n4) {
  const int i = blockIdx.x * 256 + threadIdx.x;
  if (i >= n4) return;
  const float4 v = ((const float4*)x)[i];
  short4 o;
  o.x = f2bf(v.x); o.y = f2bf(v.y); o.z = f2bf(v.z); o.w = f2bf(v.w);
  ((short4*)xb)[i] = o;
}

// ---------------- cast + transpose W -> Wt[r][n][k] bf16 ------------------
__global__ __launch_bounds__(256) void cast_wt_kernel(
    const float* __restrict__ W, short* __restrict__ wt) {
  const int o = blockIdx.x * 256 + threadIdx.x;  // over NR*256*256
  if (o >= NR * 256 * 256) return;
  const int r = o >> 16;
  const int nrow = (o >> 8) & 255;
  const int k = o & 255;
  wt[o] = f2bf(W[r * 65536 + k * 256 + nrow]);
}

// ---------------- bf16 MFMA GEMM (all relations), fused el/er epilogue ----
// Verbatim R4 structure (verified absmax 0.03125).
__global__ __launch_bounds__(256) void gemm_kernel(
    const short* __restrict__ xb,       // [NN][256] bf16
    const short* __restrict__ wt_all,   // [NR][256 n][256 k] bf16
    const float* __restrict__ attn_l,   // [NR][NH][64]
    const float* __restrict__ attn_r,   // [NR][NH][64]
    short* __restrict__ featb_all,      // [NR][MP][256] bf16
    float* __restrict__ el_all, float* __restrict__ er_all) {  // [NR][NN][NH]
  __shared__ short As[128 * 32];
  __shared__ short Bs[128 * 32];
  const int t = threadIdx.x;
  const int lane = t & 63;
  const int w = t >> 6;
  const int wm = w & 1, wn = w >> 1;
  const int row0 = blockIdx.x * 128;
  const int n0 = blockIdx.y * 128;
  const int r = blockIdx.z;
  const short* wt = wt_all + (size_t)r * 65536;
  short* featb = featb_all + (size_t)r * MP * 256;

  f32x4 acc[4][4];
#pragma unroll
  for (int mi = 0; mi < 4; ++mi)
#pragma unroll
    for (int ni = 0; ni < 4; ++ni) {
      f32x4 z = {0.f, 0.f, 0.f, 0.f};
      acc[mi][ni] = z;
    }

  const int c0 = t, c1 = 256 + t;
  int ar0 = row0 + (c0 >> 2); if (ar0 >= NN) ar0 = NN - 1;
  int ar1 = row0 + (c1 >> 2); if (ar1 >= NN) ar1 = NN - 1;
  const short* ag0 = xb + (size_t)ar0 * 256 + (c0 & 3) * 8;
  const short* ag1 = xb + (size_t)ar1 * 256 + (c1 & 3) * 8;
  const short* bg0 = wt + (size_t)(n0 + (c0 >> 2)) * 256 + (c0 & 3) * 8;
  const short* bg1 = wt + (size_t)(n0 + (c1 >> 2)) * 256 + (c1 & 3) * 8;
  short* la0 = As + c0 * 8;
  short* la1 = As + c1 * 8;
  short* lb0 = Bs + c0 * 8;
  short* lb1 = Bs + c1 * 8;

  const int ra = lane & 15;
  const int qa = (lane >> 4) * 8;

  for (int k0 = 0; k0 < 256; k0 += 32) {
    GLOAD_LDS16(ag0 + k0, la0);
    GLOAD_LDS16(ag1 + k0, la1);
    GLOAD_LDS16(bg0 + k0, lb0);
    GLOAD_LDS16(bg1 + k0, lb1);
    __syncthreads();
    bf16x8 af[4], bfr[4];
#pragma unroll
    for (int mi = 0; mi < 4; ++mi)
      af[mi] = *(const bf16x8*)&As[(wm * 64 + mi * 16 + ra) * 32 + qa];
#pragma unroll
    for (int ni = 0; ni < 4; ++ni)
      bfr[ni] = *(const bf16x8*)&Bs[(wn * 64 + ni * 16 + ra) * 32 + qa];
#pragma unroll
    for (int mi = 0; mi < 4; ++mi)
#pragma unroll
      for (int ni = 0; ni < 4; ++ni)
        acc[mi][ni] = __builtin_amdgcn_mfma_f32_16x16x32_bf16(
            af[mi], bfr[ni], acc[mi][ni], 0, 0, 0);
    __syncthreads();
  }

  const int h = (n0 >> 6) + wn;  // wave's 64-col subtile == one head
  float alv[4], arv[4];
#pragma unroll
  for (int ni = 0; ni < 4; ++ni) {
    alv[ni] = attn_l[r * HD + h * 64 + ni * 16 + ra];
    arv[ni] = attn_r[r * HD + h * 64 + ni * 16 + ra];
  }
#pragma unroll
  for (int mi = 0; mi < 4; ++mi) {
#pragma unroll
    for (int j = 0; j < 4; ++j) {
      const int row = row0 + wm * 64 + mi * 16 + (lane >> 4) * 4 + j;
      float elp = 0.f, erp = 0.f;
#pragma unroll
      for (int ni = 0; ni < 4; ++ni) {
        const float v = acc[mi][ni][j];
        featb[(size_t)row * 256 + n0 + wn * 64 + ni * 16 + ra] = f2bf(v);
        elp = fmaf(v, alv[ni], elp);
        erp = fmaf(v, arv[ni], erp);
      }
#pragma unroll
      for (int m = 1; m < 16; m <<= 1) {
        elp += __shfl_xor(elp, m, 64);
        erp += __shfl_xor(erp, m, 64);
      }
      if (ra == 0 && row < NN) {
        el_all[((size_t)r * NN + row) * NH + h] = elp;
        er_all[((size_t)r * NN + row) * NH + h] = erp;
      }
    }
  }
}

// ---------------- pack edges to u32 (dst<<16 | src) -----------------------
// NOTE: harness delivers integer inputs as int32 (NOT the reference's int64).
__global__ __launch_bounds__(256) void pack_kernel(
    const int* __restrict__ src, const int* __restrict__ dst,
    unsigned* __restrict__ pe) {
  const int i = blockIdx.x * 256 + threadIdx.x;
  if (i < NR * NE)
    pe[i] = ((unsigned)dst[i] << 16) | (unsigned)src[i];
}

// ---------------- single-pass fixed-slot bucket build ---------------------
__global__ __launch_bounds__(256) void build_kernel(
    const unsigned* __restrict__ pe, int* __restrict__ deg,
    unsigned short* __restrict__ slots) {
  const int grp = blockIdx.x & 7;
  const int chunk = blockIdx.x >> 3;
  const int lo = chunk * CHSZ;
  const int hi = (lo + CHSZ < NE) ? lo + CHSZ : NE;
  const unsigned dlo = grp * (NN / 8);
  for (int r = 0; r < NR; ++r) {
    for (int i = lo + threadIdx.x; i < hi; i += 256) {
      const unsigned p = pe[(size_t)r * NE + i];
      const unsigned d = p >> 16;
      if (d - dlo < (unsigned)(NN / 8)) {
        const int g = r * NN + (int)d;
        const int sl = atomicAdd(&deg[g], 1);
        if (sl < SLOTS)
          slots[(size_t)g * SLOTS + sl] = (unsigned short)(p & 0xffffu);
      }
    }
  }
}

// ---------------- fused all-relation aggregation, 2 edges/iteration -------
// One wave per node (4/block), NO barriers. Lanes 0-31 = edge 2j, lanes
// 32-63 = edge 2j+1; each half covers the 512B feat row at 16B/lane.
// Lane cl=lane&31: cols cl*8..cl*8+7, head h=cl>>3. Per-relation fold:
// z/acc merged across halves via shfl_xor(32), normalized, relu+bias into
// oacc; single out write at the end.
__global__ __launch_bounds__(256) void agg_kernel(
    const short* __restrict__ featb_all, const float* __restrict__ el_all,
    const float* __restrict__ er_all, const int* __restrict__ deg,
    const unsigned short* __restrict__ slots, const float* __restrict__ bias,
    float* __restrict__ out) {
  const int wid = (blockIdx.x * 256 + threadIdx.x) >> 6;  // node
  const int lane = threadIdx.x & 63;
  if (wid >= NN) return;
  const int half = lane >> 5;
  const int cl = lane & 31;
  const int h = cl >> 3;
  const int c0 = cl * 8;

  float oacc[8];
#pragma unroll
  for (int k = 0; k < 8; ++k) oacc[k] = 0.f;

  for (int r = 0; r < NR; ++r) {
    const int g = r * NN + wid;
    int dg = deg[g];
    dg = dg > SLOTS ? SLOTS : dg;
    const unsigned short* slp = slots + (size_t)g * SLOTS;
    const int sv = (lane < SLOTS) ? (int)slp[lane] : 0;  // slot row in regs
    const float er_nh = er_all[(size_t)g * NH + h];
    const float* elr = el_all + (size_t)r * NN * NH;
    const short* fb = featb_all + (size_t)r * MP * 256;

    float z = 0.f;
    float acc[8];
#pragma unroll
    for (int k = 0; k < 8; ++k) acc[k] = 0.f;

    const int iters = (dg + 1) >> 1;
    for (int j = 0; j < iters; ++j) {
      const int j2 = 2 * j + half;
      const bool valid = j2 < dg;
      int s = __shfl(sv, j2, 64);
      s = valid ? s : 0;  // keep reads in-bounds; p=0 kills contribution
      float e = elr[s * NH + h] + er_nh;
      e = fmaxf(e, 0.2f * e);  // leaky_relu(0.2)
      const float p = valid ? __expf(e) : 0.f;
      const uint4 raw = *(const uint4*)(fb + (size_t)s * 256 + c0);
      z += p;
      acc[0] = fmaf(p, bf2f_lo(raw.x), acc[0]);
      acc[1] = fmaf(p, bf2f_hi(raw.x), acc[1]);
      acc[2] = fmaf(p, bf2f_lo(raw.y), acc[2]);
      acc[3] = fmaf(p, bf2f_hi(raw.y), acc[3]);
      acc[4] = fmaf(p, bf2f_lo(raw.z), acc[4]);
      acc[5] = fmaf(p, bf2f_hi(raw.z), acc[5]);
      acc[6] = fmaf(p, bf2f_lo(raw.w), acc[6]);
      acc[7] = fmaf(p, bf2f_hi(raw.w), acc[7]);
    }
    // merge the two edge-halves (same cols, same head per xor-32 pair)
    z += __shfl_xor(z, 32, 64);
#pragma unroll
    for (int k = 0; k < 8; ++k) acc[k] += __shfl_xor(acc[k], 32, 64);
    const float inv = 1.f / fmaxf(z, 1e-9f);
    const float4 b0 = *(const float4*)(bias + r * HD + c0);
    const float4 b1 = *(const float4*)(bias + r * HD + c0 + 4);
    oacc[0] += fmaxf(fmaf(acc[0], inv, b0.x), 0.f);
    oacc[1] += fmaxf(fmaf(acc[1], inv, b0.y), 0.f);
    oacc[2] += fmaxf(fmaf(acc[2], inv, b0.z), 0.f);
    oacc[3] += fmaxf(fmaf(acc[3], inv, b0.w), 0.f);
    oacc[4] += fmaxf(fmaf(acc[4], inv, b1.x), 0.f);
    oacc[5] += fmaxf(fmaf(acc[5], inv, b1.y), 0.f);
    oacc[6] += fmaxf(fmaf(acc[6], inv, b1.z), 0.f);
    oacc[7] += fmaxf(fmaf(acc[7], inv, b1.w), 0.f);
  }
  if (half == 0) {  // both halves hold identical oacc post-merge
    float4 s0 = {oacc[0], oacc[1], oacc[2], oacc[3]};
    float4 s1 = {oacc[4], oacc[5], oacc[6], oacc[7]};
    *(float4*)(out + (size_t)wid * 256 + c0) = s0;
    *(float4*)(out + (size_t)wid * 256 + c0 + 4) = s1;
  }
}

// ---------------------------------------------------------------------------
extern "C" void kernel_launch(void* const* d_in, const int* in_sizes, int n_in,
                              void* d_out, int out_size, void* d_ws,
                              size_t ws_size, hipStream_t stream) {
  const float* x      = (const float*)d_in[0];
  const float* W      = (const float*)d_in[1];
  const float* attn_l = (const float*)d_in[2];
  const float* attn_r = (const float*)d_in[3];
  const float* bias   = (const float*)d_in[4];
  const int*   src    = (const int*)d_in[5];   // int32 per harness contract
  const int*   dst    = (const int*)d_in[6];
  float* out = (float*)d_out;

  char* p = (char*)d_ws;
  auto alloc = [&](size_t bytes) {
    char* r = p;
    p += (bytes + 255) & ~(size_t)255;
    return r;
  };
  short* xb    = (short*)alloc((size_t)NN * HD * 2);            // 25.6 MB
  short* wt    = (short*)alloc((size_t)NR * 256 * 256 * 2);     // 0.79 MB
  short* featb = (short*)alloc((size_t)NR * MP * 256 * 2);      // 153.7 MB
  float* el    = (float*)alloc((size_t)NR * NN * NH * 4);       // 4.8 MB
  float* er    = (float*)alloc((size_t)NR * NN * NH * 4);       // 4.8 MB
  int*   deg   = (int*)alloc((size_t)NR * NN * 4);              // 1.2 MB
  unsigned short* slots =
      (unsigned short*)alloc((size_t)NR * NN * SLOTS * 2);      // 19.2 MB
  unsigned* pe = (unsigned*)alloc((size_t)NR * NE * 4);         // 7.2 MB

  hipMemsetAsync(deg, 0, (size_t)NR * NN * 4, stream);

  cast_x_kernel<<<(NN * HD / 4 + 255) / 256, 256, 0, stream>>>(x, xb,
                                                               NN * HD / 4);
  cast_wt_kernel<<<(NR * 256 * 256 + 255) / 256, 256, 0, stream>>>(W, wt);
  pack_kernel<<<(NR * NE + 255) / 256, 256, 0, stream>>>(src, dst, pe);
  build_kernel<<<CHUNKS * 8, 256, 0, stream>>>(pe, deg, slots);
  gemm_kernel<<<dim3(MP / 128, 2, NR), 256, 0, stream>>>(xb, wt, attn_l,
                                                         attn_r, featb, el,
                                                         er);
  agg_kernel<<<(NN * 64) / 256, 256, 0, stream>>>(featb, el, er, deg, slots,
                                                  bias, out);
}